// Round 1
// baseline (161.623 us; speedup 1.0000x reference)
//
#include <hip/hip_runtime.h>

#define BB 128
#define GG 20000
#define HID 64
#define KB 9            // NUM_BINS - 1
#define NTOT (BB * GG)  // 2,560,000
#define EPT 4           // elements per thread
#define BLOCK 256
#define LEAKY 0.01f

__global__ __launch_bounds__(BLOCK) void expr_quant_kernel(
    const float* __restrict__ expr,
    const float* __restrict__ W1,
    const float* __restrict__ b1,
    const float* __restrict__ W2,
    const float* __restrict__ b2,
    float* __restrict__ out)
{
    __shared__ float sW1[HID];
    __shared__ float sB1[HID];
    __shared__ float sW2[HID * KB];
    __shared__ float sB2[KB];

    const int tid = threadIdx.x;
    if (tid < HID) { sW1[tid] = W1[tid]; sB1[tid] = b1[tid]; }
    for (int t = tid; t < HID * KB; t += BLOCK) sW2[t] = W2[t];
    if (tid < KB) sB2[tid] = b2[tid];
    __syncthreads();

    const int i0 = (blockIdx.x * BLOCK + tid) * EPT;  // N divisible by BLOCK*EPT: 2500 blocks exactly
    const float4 xv = *(const float4*)(expr + i0);
    float x[EPT] = {xv.x, xv.y, xv.z, xv.w};

    // logits accumulators, init with b2 (broadcast LDS reads)
    float acc[EPT][KB];
    #pragma unroll
    for (int k = 0; k < KB; ++k) {
        const float bk = sB2[k];
        #pragma unroll
        for (int e = 0; e < EPT; ++e) acc[e][k] = bk;
    }

    // MLP: h_j = leaky(x*W1[j] + b1[j]); logits_k += h_j * W2[j][k]
    #pragma unroll 8
    for (int j = 0; j < HID; ++j) {
        const float w1 = sW1[j];
        const float bb = sB1[j];
        float u[EPT];
        #pragma unroll
        for (int e = 0; e < EPT; ++e) {
            const float t = fmaf(x[e], w1, bb);
            u[e] = fmaxf(t, LEAKY * t);  // leaky relu: max(t, 0.01t) valid for both signs
        }
        #pragma unroll
        for (int k = 0; k < KB; ++k) {
            const float w2 = sW2[j * KB + k];  // 9 consecutive -> ds_read_b128 merges
            #pragma unroll
            for (int e = 0; e < EPT; ++e) acc[e][k] = fmaf(u[e], w2, acc[e][k]);
        }
    }

    // softmax over 9 bins + mask select, staged to a register tile then float4 stores
    float o[EPT * 10];
    float msk[EPT];
    #pragma unroll
    for (int e = 0; e < EPT; ++e) {
        float m = acc[e][0];
        #pragma unroll
        for (int k = 1; k < KB; ++k) m = fmaxf(m, acc[e][k]);
        float p[KB];
        float s = 0.f;
        #pragma unroll
        for (int k = 0; k < KB; ++k) { p[k] = __expf(acc[e][k] - m); s += p[k]; }
        const float r = __frcp_rn(s);
        const bool nz = (x[e] != 0.f);
        msk[e] = nz ? 1.f : 0.f;
        o[e * 10 + 0] = nz ? 0.f : 1.f;
        #pragma unroll
        for (int k = 0; k < KB; ++k) o[e * 10 + 1 + k] = nz ? p[k] * r : 0.f;
    }

    // probs: 40 contiguous floats at out[i0*10], 160B aligned
    float4* dst = (float4*)(out + (size_t)i0 * 10);
    #pragma unroll
    for (int q = 0; q < 10; ++q) dst[q] = ((const float4*)o)[q];

    // mask_expr: second output, concatenated after probs
    float4* mdst = (float4*)(out + (size_t)NTOT * 10 + i0);
    *mdst = make_float4(msk[0], msk[1], msk[2], msk[3]);
}

extern "C" void kernel_launch(void* const* d_in, const int* in_sizes, int n_in,
                              void* d_out, int out_size, void* d_ws, size_t ws_size,
                              hipStream_t stream) {
    const float* expr = (const float*)d_in[0];
    const float* W1   = (const float*)d_in[1];
    const float* b1   = (const float*)d_in[2];
    const float* W2   = (const float*)d_in[3];
    const float* b2   = (const float*)d_in[4];
    float* out = (float*)d_out;

    const int nblocks = NTOT / (BLOCK * EPT);  // 2500
    expr_quant_kernel<<<nblocks, BLOCK, 0, stream>>>(expr, W1, b1, W2, b2, out);
}

// Round 3
// 154.848 us; speedup vs baseline: 1.0438x; 1.0438x over previous
//
#include <hip/hip_runtime.h>
#include <math.h>

#define HID 64
#define KB 9            // NUM_BINS - 1
#define NB 10
#define NTOT (128 * 20000)
#define EPT 4
#define BLOCK 256
#define LEAKY 0.01f
#define RSTRIDE 20      // floats per region row (9 A + 9 C + 2 pad), 80 B keeps 16B align
#define TAB_FLOATS (128 + 65 * RSTRIDE)   // 128 padded thresholds + 65 regions = 1428
#define WS_BYTES (TAB_FLOATS * 4)
#define SENT 3.0e38f

// Piecewise-linear table: thresholds t_j = -b1_j/W1_j sorted, padded to 128
// with +SENT; per region r in [0,64], per bin k:
//   logits_k(x) = A[r][k]*x + C[r][k]   for x with count(t <= x) == r
// Unit signs per region decided at the region midpoint, iterating units in
// ORIGINAL order so (W1, b1, W2) rows stay aligned (R2 bug: sorted w/b paired
// with unsorted W2). Leaky is continuous at breakpoints, so boundary
// classification is error-free.
__device__ __forceinline__ void build_table(
    const float* __restrict__ W1, const float* __restrict__ b1,
    const float* __restrict__ W2, const float* __restrict__ b2,
    int tid, float* ts /*128*/, float* tab /*65*RSTRIDE*/,
    float* st, float* sw, float* sb, float* tsrt)
{
    if (tid < HID) {
        float w = W1[tid], b = b1[tid];
        st[tid] = (w != 0.0f) ? (-b / w) : -SENT;  // w==0: constant-sign unit, park at -inf
        sw[tid] = w; sb[tid] = b;
    }
    __syncthreads();
    if (tid < HID) {  // rank sort of thresholds only (unique ranks via index tiebreak)
        float t = st[tid];
        int r = 0;
        for (int i = 0; i < HID; ++i) {
            float ti = st[i];
            r += (ti < t || (ti == t && i < tid)) ? 1 : 0;
        }
        tsrt[r] = t;
    }
    __syncthreads();
    if (tid < 128) ts[tid] = (tid < HID) ? tsrt[tid] : SENT;
    for (int item = tid; item < 65 * KB; item += BLOCK) {
        int r = item / KB, k = item - r * KB;
        float xm;  // strictly inside region r w.r.t. every threshold
        if (r == 0)        xm = tsrt[0] - 1.0f;
        else if (r == HID) xm = tsrt[HID - 1] + 1.0f;
        else               xm = 0.5f * (tsrt[r - 1] + tsrt[r]);
        float A = 0.0f, C = b2[k];
        for (int j = 0; j < HID; ++j) {     // ORIGINAL unit order throughout
            float w = sw[j], bb = sb[j];
            float s = (fmaf(w, xm, bb) >= 0.0f) ? 1.0f : LEAKY;
            float w2s = W2[j * KB + k] * s;
            A = fmaf(w2s, w, A);
            C = fmaf(w2s, bb, C);
        }
        tab[r * RSTRIDE + k] = A;
        tab[r * RSTRIDE + KB + k] = C;
    }
    __syncthreads();
}

__device__ __forceinline__ void compute_elems(
    const float* __restrict__ expr, float* __restrict__ out,
    const float* ts, const float* tab, int i0)
{
    const float4 xv = *(const float4*)(expr + i0);
    float x[EPT] = {xv.x, xv.y, xv.z, xv.w};
    float o[EPT * NB];
    float msk[EPT];
    #pragma unroll
    for (int e = 0; e < EPT; ++e) {
        const float xe = x[e];
        // region = count of sorted thresholds <= xe; padding keeps all 7
        // probes in-bounds and xe < SENT caps idx at 64.
        int idx = 0;
        #pragma unroll
        for (int s = 64; s >= 1; s >>= 1)
            idx += (ts[idx + s - 1] <= xe) ? s : 0;
        const float* row = tab + idx * RSTRIDE;
        float lg[KB];
        #pragma unroll
        for (int k = 0; k < KB; ++k) lg[k] = fmaf(row[k], xe, row[KB + k]);
        float m = lg[0];
        #pragma unroll
        for (int k = 1; k < KB; ++k) m = fmaxf(m, lg[k]);
        float p[KB];
        float s = 0.0f;
        #pragma unroll
        for (int k = 0; k < KB; ++k) { p[k] = __expf(lg[k] - m); s += p[k]; }
        const float r = __frcp_rn(s);
        const bool nz = (xe != 0.0f);
        msk[e] = nz ? 1.0f : 0.0f;
        o[e * NB] = nz ? 0.0f : 1.0f;
        #pragma unroll
        for (int k = 0; k < KB; ++k) o[e * NB + 1 + k] = nz ? p[k] * r : 0.0f;
    }
    // probs: 40 contiguous floats, 160B aligned -> 10 float4 stores
    float4* dst = (float4*)(out + (size_t)i0 * NB);
    #pragma unroll
    for (int q = 0; q < EPT * NB / 4; ++q) dst[q] = ((const float4*)o)[q];
    // mask output, concatenated after probs
    float4* mdst = (float4*)(out + (size_t)NTOT * NB + i0);
    *mdst = make_float4(msk[0], msk[1], msk[2], msk[3]);
}

__global__ __launch_bounds__(BLOCK) void setup_kernel(
    const float* __restrict__ W1, const float* __restrict__ b1,
    const float* __restrict__ W2, const float* __restrict__ b2,
    float* __restrict__ ws)
{
    __shared__ float st[HID], sw[HID], sb[HID], tsrt[HID];
    build_table(W1, b1, W2, b2, threadIdx.x, ws, ws + 128, st, sw, sb, tsrt);
}

__global__ __launch_bounds__(BLOCK) void main_kernel(
    const float* __restrict__ expr, const float* __restrict__ ws,
    float* __restrict__ out)
{
    __shared__ float ts[128];
    __shared__ float tab[65 * RSTRIDE];
    const int tid = threadIdx.x;
    for (int t = tid; t < TAB_FLOATS; t += BLOCK) {
        float v = ws[t];
        if (t < 128) ts[t] = v; else tab[t - 128] = v;
    }
    __syncthreads();
    const int i0 = (blockIdx.x * BLOCK + tid) * EPT;
    compute_elems(expr, out, ts, tab, i0);
}

// Fallback if d_ws is too small: build the table per-block in LDS (redundant
// compute, but correct and self-contained).
__global__ __launch_bounds__(BLOCK) void fused_kernel(
    const float* __restrict__ expr,
    const float* __restrict__ W1, const float* __restrict__ b1,
    const float* __restrict__ W2, const float* __restrict__ b2,
    float* __restrict__ out)
{
    __shared__ float ts[128];
    __shared__ float tab[65 * RSTRIDE];
    __shared__ float st[HID], sw[HID], sb[HID], tsrt[HID];
    build_table(W1, b1, W2, b2, threadIdx.x, ts, tab, st, sw, sb, tsrt);
    const int i0 = (blockIdx.x * BLOCK + threadIdx.x) * EPT;
    compute_elems(expr, out, ts, tab, i0);
}

extern "C" void kernel_launch(void* const* d_in, const int* in_sizes, int n_in,
                              void* d_out, int out_size, void* d_ws, size_t ws_size,
                              hipStream_t stream) {
    const float* expr = (const float*)d_in[0];
    const float* W1   = (const float*)d_in[1];
    const float* b1   = (const float*)d_in[2];
    const float* W2   = (const float*)d_in[3];
    const float* b2   = (const float*)d_in[4];
    float* out = (float*)d_out;
    const int nblocks = NTOT / (BLOCK * EPT);  // 2500

    if (ws_size >= (size_t)WS_BYTES) {
        float* ws = (float*)d_ws;
        setup_kernel<<<1, BLOCK, 0, stream>>>(W1, b1, W2, b2, ws);
        main_kernel<<<nblocks, BLOCK, 0, stream>>>(expr, ws, out);
    } else {
        fused_kernel<<<nblocks, BLOCK, 0, stream>>>(expr, W1, b1, W2, b2, out);
    }
}

// Round 4
// 141.877 us; speedup vs baseline: 1.1392x; 1.0914x over previous
//
#include <hip/hip_runtime.h>
#include <math.h>

#define HID 64
#define KB 9            // NUM_BINS - 1
#define NB 10
#define NTOT (128 * 20000)
#define EPT 4
#define BLOCK 256
#define LEAKY 0.01f
#define RSTRIDE 20      // floats per region row (9 A + 9 C + 2 pad)
#define TAB_FLOATS (128 + 65 * RSTRIDE)   // 128 padded thresholds + 65 regions = 1428
#define WS_BYTES (TAB_FLOATS * 4)
#define SENT 3.0e38f

// ---------------- setup: 65 blocks x 64 threads, one region per wave ----------------
// ws[0..127]   : sorted thresholds t_j = -b1_j/W1_j, padded with +SENT
// ws[128 + r*RSTRIDE + k]      : A[r][k]
// ws[128 + r*RSTRIDE + KB + k] : C[r][k]
// logits_k(x) = A*x + C on region r = count(t <= x). Unit order stays ORIGINAL
// (R2 bug); sort affects only the threshold array.
__global__ __launch_bounds__(64) void setup_kernel(
    const float* __restrict__ W1, const float* __restrict__ b1,
    const float* __restrict__ W2, const float* __restrict__ b2,
    float* __restrict__ ws)
{
    __shared__ float t_lds[HID], w_lds[HID], b_lds[HID], tsrt[HID];
    __shared__ float w2_lds[HID * KB];
    __shared__ float red[18 * 65];   // 18 rows padded to 65 -> conflict-free reduce

    const int j = threadIdx.x;       // unit index (original order)
    const int r = blockIdx.x;        // region index 0..64
    const float w = W1[j], b = b1[j];
    const float t = (w != 0.0f) ? (-b / w) : -SENT;  // w==0: constant sign, park at -inf
    t_lds[j] = t; w_lds[j] = w; b_lds[j] = b;
    #pragma unroll
    for (int q = j; q < HID * KB; q += 64) w2_lds[q] = W2[q];
    __syncthreads();

    // rank sort of thresholds (unique ranks via index tiebreak)
    int rank = 0;
    for (int i = 0; i < HID; ++i) {
        float ti = t_lds[i];
        rank += (ti < t || (ti == t && i < j)) ? 1 : 0;
    }
    tsrt[rank] = t;
    __syncthreads();

    float xm;   // point strictly inside region r
    if (r == 0)        xm = tsrt[0] - 1.0f;
    else if (r == HID) xm = tsrt[HID - 1] + 1.0f;
    else               xm = 0.5f * (tsrt[r - 1] + tsrt[r]);

    const float s = (fmaf(w, xm, b) >= 0.0f) ? 1.0f : LEAKY;
    #pragma unroll
    for (int k = 0; k < KB; ++k) {
        const float w2s = w2_lds[j * KB + k] * s;
        red[(2 * k) * 65 + j]     = w2s * w;   // A contribution
        red[(2 * k + 1) * 65 + j] = w2s * b;   // C contribution
    }
    __syncthreads();

    if (j < 18) {   // threads 0..17 each sum one row of 64 (deterministic order)
        float acc = 0.0f;
        for (int i = 0; i < HID; ++i) acc += red[j * 65 + i];
        const int k = j >> 1;
        if (j & 1) ws[128 + r * RSTRIDE + KB + k] = acc + b2[k];  // C
        else       ws[128 + r * RSTRIDE + k]      = acc;          // A
    }
    if (r == 0) { ws[j] = tsrt[j]; ws[64 + j] = SENT; }
}

// ---------------- main: table lookup + softmax, LDS-staged coalesced stores ----------------
__global__ __launch_bounds__(BLOCK) void main_kernel(
    const float* __restrict__ expr, const float* __restrict__ ws,
    float* __restrict__ out)
{
    __shared__ float ts[128];
    __shared__ float tab[65 * RSTRIDE];
    __shared__ float so[BLOCK * EPT * NB];   // 10240 floats = 40 KB probs staging

    const int tid = threadIdx.x;
    for (int t = tid; t < TAB_FLOATS; t += BLOCK) {
        float v = ws[t];
        if (t < 128) ts[t] = v; else tab[t - 128] = v;
    }
    __syncthreads();

    const int i0 = (blockIdx.x * BLOCK + tid) * EPT;
    const float4 xv = *(const float4*)(expr + i0);
    float x[EPT] = {xv.x, xv.y, xv.z, xv.w};
    float o[EPT * NB];
    float msk[EPT];
    #pragma unroll
    for (int e = 0; e < EPT; ++e) {
        const float xe = x[e];
        // region = count(sorted thresholds <= xe); padding keeps 7 probes in-bounds
        int idx = 0;
        #pragma unroll
        for (int s = 64; s >= 1; s >>= 1)
            idx += (ts[idx + s - 1] <= xe) ? s : 0;
        const float* row = tab + idx * RSTRIDE;
        float lg[KB];
        #pragma unroll
        for (int k = 0; k < KB; ++k) lg[k] = fmaf(row[k], xe, row[KB + k]);
        float m = lg[0];
        #pragma unroll
        for (int k = 1; k < KB; ++k) m = fmaxf(m, lg[k]);
        float p[KB];
        float s = 0.0f;
        #pragma unroll
        for (int k = 0; k < KB; ++k) { p[k] = __expf(lg[k] - m); s += p[k]; }
        const float rcp = __frcp_rn(s);
        const bool nz = (xe != 0.0f);
        msk[e] = nz ? 1.0f : 0.0f;
        o[e * NB] = nz ? 0.0f : 1.0f;
        #pragma unroll
        for (int k = 0; k < KB; ++k) o[e * NB + 1 + k] = nz ? p[k] * rcp : 0.0f;
    }

    // mask output: lane-contiguous float4 stores (already coalesced)
    *(float4*)(out + (size_t)NTOT * NB + i0) = make_float4(msk[0], msk[1], msk[2], msk[3]);

    // probs: stage to LDS, then re-read linearly for 1KB-contiguous wave stores
    #pragma unroll
    for (int q = 0; q < NB; ++q)
        ((float4*)so)[tid * NB + q] = ((const float4*)o)[q];
    __syncthreads();
    float* gout = out + (size_t)blockIdx.x * (BLOCK * EPT * NB);
    #pragma unroll
    for (int q = 0; q < NB; ++q) {
        const int f4 = q * BLOCK + tid;           // linear float4 index in block tile
        *(float4*)(gout + f4 * 4) = ((const float4*)so)[f4];
    }
}

// ---------------- fallback if d_ws too small: self-contained, per-block table ----------------
__global__ __launch_bounds__(BLOCK) void fused_kernel(
    const float* __restrict__ expr,
    const float* __restrict__ W1, const float* __restrict__ b1,
    const float* __restrict__ W2, const float* __restrict__ b2,
    float* __restrict__ out)
{
    __shared__ float ts[128];
    __shared__ float tab[65 * RSTRIDE];
    __shared__ float st[HID], sw[HID], sb[HID], tsrt[HID];
    const int tid = threadIdx.x;
    if (tid < HID) {
        float w = W1[tid], b = b1[tid];
        st[tid] = (w != 0.0f) ? (-b / w) : -SENT;
        sw[tid] = w; sb[tid] = b;
    }
    __syncthreads();
    if (tid < HID) {
        float t = st[tid];
        int r = 0;
        for (int i = 0; i < HID; ++i) {
            float ti = st[i];
            r += (ti < t || (ti == t && i < tid)) ? 1 : 0;
        }
        tsrt[r] = t;
    }
    __syncthreads();
    if (tid < 128) ts[tid] = (tid < HID) ? tsrt[tid] : SENT;
    for (int item = tid; item < 65 * KB; item += BLOCK) {
        int r = item / KB, k = item - r * KB;
        float xm;
        if (r == 0)        xm = tsrt[0] - 1.0f;
        else if (r == HID) xm = tsrt[HID - 1] + 1.0f;
        else               xm = 0.5f * (tsrt[r - 1] + tsrt[r]);
        float A = 0.0f, C = b2[k];
        for (int j = 0; j < HID; ++j) {
            float w = sw[j], bb = sb[j];
            float s = (fmaf(w, xm, bb) >= 0.0f) ? 1.0f : LEAKY;
            float w2s = W2[j * KB + k] * s;
            A = fmaf(w2s, w, A);
            C = fmaf(w2s, bb, C);
        }
        tab[r * RSTRIDE + k] = A;
        tab[r * RSTRIDE + KB + k] = C;
    }
    __syncthreads();
    const int i0 = (blockIdx.x * BLOCK + tid) * EPT;
    const float4 xv = *(const float4*)(expr + i0);
    float x[EPT] = {xv.x, xv.y, xv.z, xv.w};
    float o[EPT * NB]; float msk[EPT];
    #pragma unroll
    for (int e = 0; e < EPT; ++e) {
        const float xe = x[e];
        int idx = 0;
        #pragma unroll
        for (int s = 64; s >= 1; s >>= 1) idx += (ts[idx + s - 1] <= xe) ? s : 0;
        const float* row = tab + idx * RSTRIDE;
        float lg[KB];
        #pragma unroll
        for (int k = 0; k < KB; ++k) lg[k] = fmaf(row[k], xe, row[KB + k]);
        float m = lg[0];
        #pragma unroll
        for (int k = 1; k < KB; ++k) m = fmaxf(m, lg[k]);
        float p[KB]; float s = 0.0f;
        #pragma unroll
        for (int k = 0; k < KB; ++k) { p[k] = __expf(lg[k] - m); s += p[k]; }
        const float rcp = __frcp_rn(s);
        const bool nz = (xe != 0.0f);
        msk[e] = nz ? 1.0f : 0.0f;
        o[e * NB] = nz ? 0.0f : 1.0f;
        #pragma unroll
        for (int k = 0; k < KB; ++k) o[e * NB + 1 + k] = nz ? p[k] * rcp : 0.0f;
    }
    float4* dst = (float4*)(out + (size_t)i0 * NB);
    #pragma unroll
    for (int q = 0; q < EPT * NB / 4; ++q) dst[q] = ((const float4*)o)[q];
    *(float4*)(out + (size_t)NTOT * NB + i0) = make_float4(msk[0], msk[1], msk[2], msk[3]);
}

extern "C" void kernel_launch(void* const* d_in, const int* in_sizes, int n_in,
                              void* d_out, int out_size, void* d_ws, size_t ws_size,
                              hipStream_t stream) {
    const float* expr = (const float*)d_in[0];
    const float* W1   = (const float*)d_in[1];
    const float* b1   = (const float*)d_in[2];
    const float* W2   = (const float*)d_in[3];
    const float* b2   = (const float*)d_in[4];
    float* out = (float*)d_out;
    const int nblocks = NTOT / (BLOCK * EPT);  // 2500

    if (ws_size >= (size_t)WS_BYTES) {
        float* ws = (float*)d_ws;
        setup_kernel<<<65, 64, 0, stream>>>(W1, b1, W2, b2, ws);
        main_kernel<<<nblocks, BLOCK, 0, stream>>>(expr, ws, out);
    } else {
        fused_kernel<<<nblocks, BLOCK, 0, stream>>>(expr, W1, b1, W2, b2, out);
    }
}